// Round 12
// baseline (106.276 us; speedup 1.0000x reference)
//
#include <hip/hip_runtime.h>

// AttentionNet N=128, a1=a2=64, f=2 — R12: R10 partitioning (grid 2N=256,
// 2 blocks per n, rows half*32+wv*2, full k) + R10 inner loop, but the
// exchange/softmax is fully de-serialized:
//   * every wave polls all 64 encoded m-slots itself (1 global load/retry)
//     and computes softmax redundantly in registers (DPP) — no wave0-only
//     critical section, no LDS m/v buffers
//   * v1[ti] via 4 uniform readlanes + selects; v2[tj+t] via 4 __shfl
//   * barriers: 9 -> 5 (publish + WAR per stage, none after last)

constexpr int A   = 64;
constexpr int PAD = 68;   // floats; 272 B row stride: 16B-aligned
constexpr float L2E  = 1.4426950408889634f;
constexpr float EPSF = 1e-6f;

__device__ __forceinline__ float bcast(float v, int srcLane) {
    return __int_as_float(__builtin_amdgcn_readlane(__float_as_int(v), srcLane));
}
__device__ __forceinline__ float rcpf(float v) { return __builtin_amdgcn_rcpf(v); }
__device__ __forceinline__ float ex2(float v)  { return __builtin_amdgcn_exp2f(v); }

// DPP wave64 reductions on the VALU pipe (identity 0 ok: values >= 0).
template <int CTRL>
__device__ __forceinline__ float upd_dpp(float src) {
    return __int_as_float(__builtin_amdgcn_update_dpp(
        0, __float_as_int(src), CTRL, 0xF, 0xF, true));
}
__device__ __forceinline__ float wave_sum64(float x) {
    x += upd_dpp<0x111>(x);
    x += upd_dpp<0x112>(x);
    x += upd_dpp<0x114>(x);
    x += upd_dpp<0x118>(x);
    x += upd_dpp<0x142>(x);   // row_bcast:15
    x += upd_dpp<0x143>(x);   // row_bcast:31
    return bcast(x, 63);
}
__device__ __forceinline__ float wave_max64(float x) {
    x = fmaxf(x, upd_dpp<0x111>(x));
    x = fmaxf(x, upd_dpp<0x112>(x));
    x = fmaxf(x, upd_dpp<0x114>(x));
    x = fmaxf(x, upd_dpp<0x118>(x));
    x = fmaxf(x, upd_dpp<0x142>(x));
    x = fmaxf(x, upd_dpp<0x143>(x));
    return bcast(x, 63);
}

// Reduce rows row0,row0+1 (lane <-> column j); lane0 stores encoded m
// (m+2.0 in [2,4): sign 0, exp 128 -> self-validating vs 0xAA poison/zeros).
__device__ __forceinline__ void att2q(const float* __restrict__ prow,
                                      const float* __restrict__ qL,
                                      int row0, int lane,
                                      float* __restrict__ mg)
{
    const float qreg0 = qL[row0 * PAD + lane];
    const float qreg1 = qL[(row0 + 1) * PAD + lane];
    float acc0 = 0.f, acc1 = 0.f;
#pragma unroll 1
    for (int c = 0; c < 4; ++c) {
        float pk[16];                                    // 4x ds_read_b128
        *(float4*)(&pk[0])  = *(const float4*)(prow + c * 16 + 0);
        *(float4*)(&pk[4])  = *(const float4*)(prow + c * 16 + 4);
        *(float4*)(&pk[8])  = *(const float4*)(prow + c * 16 + 8);
        *(float4*)(&pk[12]) = *(const float4*)(prow + c * 16 + 12);
#pragma unroll
        for (int t = 0; t < 8; ++t) {                    // k-pairs, pairwise rcp
            const int k0 = c * 16 + 2 * t, k1 = k0 + 1;
            {
                float u0 = fmaf(pk[2 * t],     bcast(qreg0, k0), 1.0f);
                float u1 = fmaf(pk[2 * t + 1], bcast(qreg0, k1), 1.0f);
                acc0 = fmaf(u0 + u1, rcpf(u0 * u1), acc0);
            }
            {
                float u0 = fmaf(pk[2 * t],     bcast(qreg1, k0), 1.0f);
                float u1 = fmaf(pk[2 * t + 1], bcast(qreg1, k1), 1.0f);
                acc1 = fmaf(u0 + u1, rcpf(u0 * u1), acc1);
            }
        }
    }
    const float s0 = wave_sum64(acc0), m0 = wave_max64(acc0);
    const float s1 = wave_sum64(acc1), m1 = wave_max64(acc1);
    if (lane == 0) {
        float v0 = (s0 * (1.0f / 4096.0f)) / (m0 * (1.0f / 64.0f) + EPSF);
        float v1 = (s1 * (1.0f / 4096.0f)) / (m1 * (1.0f / 64.0f) + EPSF);
        __hip_atomic_store(mg + row0,     v0 + 2.0f, __ATOMIC_RELAXED, __HIP_MEMORY_SCOPE_AGENT);
        __hip_atomic_store(mg + row0 + 1, v1 + 2.0f, __ATOMIC_RELAXED, __HIP_MEMORY_SCOPE_AGENT);
    }
}

// Every wave: one vectorized load of the 64 slots, retry until all valid.
__device__ __forceinline__ float poll_all(const float* __restrict__ mg, int lane)
{
    for (;;) {
        float f = __hip_atomic_load(mg + lane, __ATOMIC_RELAXED, __HIP_MEMORY_SCOPE_AGENT);
        unsigned u = __float_as_uint(f);
        if (__all((u >> 23) == 0x80u)) return f - 2.0f;
        __builtin_amdgcn_s_sleep(1);
    }
}

__device__ __forceinline__ float softmax64(float m, float sharp, float th, bool last)
{
    float v = fmaxf(0.f, m * sharp + th);
    float mx = wave_max64(v);
    float e = __expf(v - mx);
    float s = wave_sum64(e);
    float r = e / s;
    if (!last) {
        float rm = wave_max64(r);
        r = r / (rm + EPSF);
    }
    return r;
}

// v[4*wv + (lane>>4)] from this wave's own softmax register.
__device__ __forceinline__ float gather4(float v, int wv, int lane)
{
    float r0 = bcast(v, 4 * wv + 0);
    float r1 = bcast(v, 4 * wv + 1);
    float r2 = bcast(v, 4 * wv + 2);
    float r3 = bcast(v, 4 * wv + 3);
    int g = (lane >> 4) & 3;
    float lo = (g & 1) ? r1 : r0;
    float hi = (g & 1) ? r3 : r2;
    return (g & 2) ? hi : lo;
}

__global__ __launch_bounds__(1024, 4)
void attn_half(const float* __restrict__ x,
               const float* __restrict__ fcW, const float* __restrict__ fcb,
               const float* __restrict__ p1W, const float* __restrict__ p1b,
               const float* __restrict__ p1s, const float* __restrict__ p1t,
               const float* __restrict__ p2W, const float* __restrict__ p2b,
               const float* __restrict__ p2s, const float* __restrict__ p2t,
               const float* __restrict__ oW,  const float* __restrict__ ob,
               const float* __restrict__ os,  const float* __restrict__ ot,
               float* __restrict__ mglob,     // [N][3][64]
               float* __restrict__ out)
{
    __shared__ __align__(16) float pL[A * PAD];
    __shared__ __align__(16) float qL[A * PAD];

    const int tid = threadIdx.x, lane = tid & 63, wv = tid >> 6;
    const int n = blockIdx.x >> 1, half = blockIdx.x & 1;
    const int row0 = half * 32 + wv * 2;
    const int i = tid >> 4, j = (tid & 15) * 4;
    float* mg = mglob + (size_t)n * 3 * A;

    // ---- x loaded once; h0/h1 live in registers ----
    const float4* x0v = (const float4*)(x + (size_t)n * 2 * A * A);
    const float4* x1v = x0v + (A * A / 4);
    const float4 a = x0v[tid];
    const float4 c = x1v[tid];
    const float w00 = fcW[0], w01 = fcW[1], w10 = fcW[2], w11 = fcW[3];
    const float b0 = fcb[0], b1 = fcb[1];
    const float h0v[4] = { fmaxf(0.f, w00 * a.x + w01 * c.x + b0),
                           fmaxf(0.f, w00 * a.y + w01 * c.y + b0),
                           fmaxf(0.f, w00 * a.z + w01 * c.z + b0),
                           fmaxf(0.f, w00 * a.w + w01 * c.w + b0) };
    const float h1v[4] = { fmaxf(0.f, w10 * a.x + w11 * c.x + b1),
                           fmaxf(0.f, w10 * a.y + w11 * c.y + b1),
                           fmaxf(0.f, w10 * a.z + w11 * c.z + b1),
                           fmaxf(0.f, w10 * a.w + w11 * c.w + b1) };

    // ======== stage B: X = h0 (row-major, float4 stores) ========
    {
        const float W0 = p1W[0], W1 = p1W[1], bb = p1b[0];
        float4 pv, qv;
        pv.x = ex2(-L2E * (W0 * h0v[0] + bb)); qv.x = ex2(-L2E * (W1 * h0v[0]));
        pv.y = ex2(-L2E * (W0 * h0v[1] + bb)); qv.y = ex2(-L2E * (W1 * h0v[1]));
        pv.z = ex2(-L2E * (W0 * h0v[2] + bb)); qv.z = ex2(-L2E * (W1 * h0v[2]));
        pv.w = ex2(-L2E * (W0 * h0v[3] + bb)); qv.w = ex2(-L2E * (W1 * h0v[3]));
        *(float4*)&pL[i * PAD + j] = pv;
        *(float4*)&qL[i * PAD + j] = qv;
    }
    __syncthreads();                                   // B1: tiles published
    att2q(pL + lane * PAD, qL, row0, lane, mg);
    const float v1reg = softmax64(poll_all(mg, lane), p1s[0], p1t[0], false);
    __syncthreads();                                   // B2: WAR on tiles

    // ======== stage C: X[r][k] = h1[k][r] * v1[k] (transposed stores) ========
    const float sc1 = gather4(v1reg, wv, lane);        // v1[i], i = tid>>4
    {
        const float W0 = p2W[0], W1 = p2W[1], bb = p2b[0];
#pragma unroll
        for (int t = 0; t < 4; ++t) {
            float hv = h1v[t] * sc1;
            pL[(j + t) * PAD + i] = ex2(-L2E * (W0 * hv + bb));
            qL[(j + t) * PAD + i] = ex2(-L2E * (W1 * hv));
        }
    }
    __syncthreads();                                   // B3: tiles published
    att2q(pL + lane * PAD, qL, row0, lane, mg + A);
    const float v2reg = softmax64(poll_all(mg + A, lane), p2s[0], p2t[0], false);
    __syncthreads();                                   // B4: WAR on tiles

    // ======== stage D: X = h0 * v1[i] * v2[j] (row-major, float4 stores) ====
    {
        const float W0 = oW[0], W1 = oW[1], bb = ob[0];
        float pv[4], qv[4];
#pragma unroll
        for (int t = 0; t < 4; ++t) {
            float v2t = __shfl(v2reg, j + t, 64);
            float hv = h0v[t] * sc1 * v2t;
            pv[t] = ex2(-L2E * (W0 * hv + bb));
            qv[t] = ex2(-L2E * (W1 * hv));
        }
        *(float4*)&pL[i * PAD + j] = *(float4*)&pv[0];
        *(float4*)&qL[i * PAD + j] = *(float4*)&qv[0];
    }
    __syncthreads();                                   // B5: tiles published
    att2q(pL + lane * PAD, qL, row0, lane, mg + 2 * A);

    // ======== final softmax (is_last): half0/wave0 writes all 64 ========
    if (half == 0 && wv == 0) {
        float r = softmax64(poll_all(mg + 2 * A, lane), os[0], ot[0], true);
        out[(size_t)n * A + lane] = r;
    }
}

extern "C" void kernel_launch(void* const* d_in, const int* in_sizes, int n_in,
                              void* d_out, int out_size, void* d_ws, size_t ws_size,
                              hipStream_t stream)
{
    (void)n_in; (void)out_size; (void)ws_size;
    const float* x   = (const float*)d_in[0];
    const float* fcW = (const float*)d_in[1];
    const float* fcb = (const float*)d_in[2];
    const float* p1W = (const float*)d_in[3];
    const float* p1b = (const float*)d_in[4];
    const float* p1s = (const float*)d_in[5];
    const float* p1t = (const float*)d_in[6];
    const float* p2W = (const float*)d_in[7];
    const float* p2b = (const float*)d_in[8];
    const float* p2s = (const float*)d_in[9];
    const float* p2t = (const float*)d_in[10];
    const float* oW  = (const float*)d_in[11];
    const float* ob  = (const float*)d_in[12];
    const float* os  = (const float*)d_in[13];
    const float* ot  = (const float*)d_in[14];
    float* out = (float*)d_out;

    const int N = in_sizes[0] / (2 * A * A);   // 128
    float* mglob = (float*)d_ws;               // [N][3][64]

    attn_half<<<2 * N, 1024, 0, stream>>>(x, fcW, fcb,
                                          p1W, p1b, p1s, p1t,
                                          p2W, p2b, p2s, p2t,
                                          oW, ob, os, ot, mglob, out);
}

// Round 13
// 99.688 us; speedup vs baseline: 1.0661x; 1.0661x over previous
//
#include <hip/hip_runtime.h>

// AttentionNet N=128, a1=a2=64, f=2 — R13: R10 base (best: fused single
// launch, grid 2N=256, 2 blocks/n, wave0 exch+softmax via LDS mbuf + encoded
// global slots, DPP reductions, b128 p-loads, PAD 68) with att2q upgraded:
//   * chunk loop fully unrolled -> ds_read_b128 hoisted/pipelined (no
//     per-chunk lgkmcnt stall exposure at 4 waves/SIMD)
//   * 4-way rcp batching: one v_rcp per FOUR sigmoids
//     1/u0+1/u1+1/u2+1/u3 = ((u0+u1)u2u3 + (u2+u3)u0u1) / (u0u1u2u3)

constexpr int A   = 64;
constexpr int PAD = 68;   // floats; 272 B row stride: 16B-aligned
constexpr float L2E  = 1.4426950408889634f;
constexpr float EPSF = 1e-6f;

__device__ __forceinline__ float bcast(float v, int srcLane) {
    return __int_as_float(__builtin_amdgcn_readlane(__float_as_int(v), srcLane));
}
__device__ __forceinline__ float rcpf(float v) { return __builtin_amdgcn_rcpf(v); }
__device__ __forceinline__ float ex2(float v)  { return __builtin_amdgcn_exp2f(v); }

// DPP wave64 reductions on the VALU pipe (identity 0 ok: values >= 0).
template <int CTRL>
__device__ __forceinline__ float upd_dpp(float src) {
    return __int_as_float(__builtin_amdgcn_update_dpp(
        0, __float_as_int(src), CTRL, 0xF, 0xF, true));
}
__device__ __forceinline__ float wave_sum64(float x) {
    x += upd_dpp<0x111>(x);
    x += upd_dpp<0x112>(x);
    x += upd_dpp<0x114>(x);
    x += upd_dpp<0x118>(x);
    x += upd_dpp<0x142>(x);   // row_bcast:15
    x += upd_dpp<0x143>(x);   // row_bcast:31
    return bcast(x, 63);
}
__device__ __forceinline__ float wave_max64(float x) {
    x = fmaxf(x, upd_dpp<0x111>(x));
    x = fmaxf(x, upd_dpp<0x112>(x));
    x = fmaxf(x, upd_dpp<0x114>(x));
    x = fmaxf(x, upd_dpp<0x118>(x));
    x = fmaxf(x, upd_dpp<0x142>(x));
    x = fmaxf(x, upd_dpp<0x143>(x));
    return bcast(x, 63);
}

// Reduce rows row0,row0+1 (lane <-> column j). lane0 writes LDS mbuf and the
// encoded global slot (m+2.0: sign 0, exp 128 -> self-validating vs poison).
__device__ __forceinline__ void att2q(const float* __restrict__ prow,
                                      const float* __restrict__ qL,
                                      int row0, int lane,
                                      float* __restrict__ mbuf,
                                      float* __restrict__ mg)
{
    const float qreg0 = qL[row0 * PAD + lane];
    const float qreg1 = qL[(row0 + 1) * PAD + lane];
    float acc0 = 0.f, acc1 = 0.f;
#pragma unroll
    for (int c = 0; c < 4; ++c) {
        float pk[16];                                    // 4x ds_read_b128
        *(float4*)(&pk[0])  = *(const float4*)(prow + c * 16 + 0);
        *(float4*)(&pk[4])  = *(const float4*)(prow + c * 16 + 4);
        *(float4*)(&pk[8])  = *(const float4*)(prow + c * 16 + 8);
        *(float4*)(&pk[12]) = *(const float4*)(prow + c * 16 + 12);
#pragma unroll
        for (int g = 0; g < 4; ++g) {                    // 4-way rcp groups
            const int k = c * 16 + 4 * g;
            const float p0 = pk[4 * g], p1 = pk[4 * g + 1];
            const float p2 = pk[4 * g + 2], p3 = pk[4 * g + 3];
            {   // row 0
                float u0 = fmaf(p0, bcast(qreg0, k),     1.0f);
                float u1 = fmaf(p1, bcast(qreg0, k + 1), 1.0f);
                float u2 = fmaf(p2, bcast(qreg0, k + 2), 1.0f);
                float u3 = fmaf(p3, bcast(qreg0, k + 3), 1.0f);
                float a = u0 * u1, b = u2 * u3;
                float numer = fmaf(u0 + u1, b, (u2 + u3) * a);
                acc0 = fmaf(numer, rcpf(a * b), acc0);
            }
            {   // row 1
                float u0 = fmaf(p0, bcast(qreg1, k),     1.0f);
                float u1 = fmaf(p1, bcast(qreg1, k + 1), 1.0f);
                float u2 = fmaf(p2, bcast(qreg1, k + 2), 1.0f);
                float u3 = fmaf(p3, bcast(qreg1, k + 3), 1.0f);
                float a = u0 * u1, b = u2 * u3;
                float numer = fmaf(u0 + u1, b, (u2 + u3) * a);
                acc1 = fmaf(numer, rcpf(a * b), acc1);
            }
        }
    }
    const float s0 = wave_sum64(acc0), m0 = wave_max64(acc0);
    const float s1 = wave_sum64(acc1), m1 = wave_max64(acc1);
    if (lane == 0) {
        float v0 = (s0 * (1.0f / 4096.0f)) / (m0 * (1.0f / 64.0f) + EPSF);
        float v1 = (s1 * (1.0f / 4096.0f)) / (m1 * (1.0f / 64.0f) + EPSF);
        mbuf[row0]     = v0;
        mbuf[row0 + 1] = v1;
        __hip_atomic_store(mg + row0,     v0 + 2.0f, __ATOMIC_RELAXED, __HIP_MEMORY_SCOPE_AGENT);
        __hip_atomic_store(mg + row0 + 1, v1 + 2.0f, __ATOMIC_RELAXED, __HIP_MEMORY_SCOPE_AGENT);
    }
}

__device__ __forceinline__ float softmax64(float m, float sharp, float th, bool last)
{
    float v = fmaxf(0.f, m * sharp + th);
    float mx = wave_max64(v);
    float e = __expf(v - mx);
    float s = wave_sum64(e);
    float r = e / s;
    if (!last) {
        float rm = wave_max64(r);
        r = r / (rm + EPSF);
    }
    return r;
}

// Wave-0 only: own half's m from LDS, peer half via spin on encoded slots.
__device__ __forceinline__ float exch_soft(const float* __restrict__ mbuf,
                                           const float* __restrict__ mg,
                                           int half, int lane,
                                           float sharp, float th, bool last)
{
    float mv;
    if ((lane >> 5) == half) {
        mv = mbuf[lane];
    } else {
        const float* p = mg + lane;
        for (;;) {
            float f = __hip_atomic_load(p, __ATOMIC_RELAXED, __HIP_MEMORY_SCOPE_AGENT);
            unsigned u = __float_as_uint(f);
            if ((u >> 23) == 0x80u) { mv = f - 2.0f; break; }   // sign 0, exp 128
            __builtin_amdgcn_s_sleep(1);
        }
    }
    return softmax64(mv, sharp, th, last);
}

__global__ __launch_bounds__(1024, 4)
void attn_half(const float* __restrict__ x,
               const float* __restrict__ fcW, const float* __restrict__ fcb,
               const float* __restrict__ p1W, const float* __restrict__ p1b,
               const float* __restrict__ p1s, const float* __restrict__ p1t,
               const float* __restrict__ p2W, const float* __restrict__ p2b,
               const float* __restrict__ p2s, const float* __restrict__ p2t,
               const float* __restrict__ oW,  const float* __restrict__ ob,
               const float* __restrict__ os,  const float* __restrict__ ot,
               float* __restrict__ mglob,     // [N][3][64]
               float* __restrict__ out)
{
    __shared__ __align__(16) float pL[A * PAD];
    __shared__ __align__(16) float qL[A * PAD];
    __shared__ float mbuf[A];
    __shared__ float v1buf[A], v2buf[A];

    const int tid = threadIdx.x, lane = tid & 63, wv = tid >> 6;
    const int n = blockIdx.x >> 1, half = blockIdx.x & 1;
    const int row0 = half * 32 + wv * 2;
    const int i = tid >> 4, j = (tid & 15) * 4;
    float* mg = mglob + (size_t)n * 3 * A;

    // ---- x loaded once; h0/h1 live in registers ----
    const float4* x0v = (const float4*)(x + (size_t)n * 2 * A * A);
    const float4* x1v = x0v + (A * A / 4);
    const float4 a = x0v[tid];
    const float4 c = x1v[tid];
    const float w00 = fcW[0], w01 = fcW[1], w10 = fcW[2], w11 = fcW[3];
    const float b0 = fcb[0], b1 = fcb[1];
    const float h0v[4] = { fmaxf(0.f, w00 * a.x + w01 * c.x + b0),
                           fmaxf(0.f, w00 * a.y + w01 * c.y + b0),
                           fmaxf(0.f, w00 * a.z + w01 * c.z + b0),
                           fmaxf(0.f, w00 * a.w + w01 * c.w + b0) };
    const float h1v[4] = { fmaxf(0.f, w10 * a.x + w11 * c.x + b1),
                           fmaxf(0.f, w10 * a.y + w11 * c.y + b1),
                           fmaxf(0.f, w10 * a.z + w11 * c.z + b1),
                           fmaxf(0.f, w10 * a.w + w11 * c.w + b1) };

    // ======== stage B: X = h0 (row-major, float4 stores) ========
    {
        const float W0 = p1W[0], W1 = p1W[1], bb = p1b[0];
        float4 pv, qv;
        pv.x = ex2(-L2E * (W0 * h0v[0] + bb)); qv.x = ex2(-L2E * (W1 * h0v[0]));
        pv.y = ex2(-L2E * (W0 * h0v[1] + bb)); qv.y = ex2(-L2E * (W1 * h0v[1]));
        pv.z = ex2(-L2E * (W0 * h0v[2] + bb)); qv.z = ex2(-L2E * (W1 * h0v[2]));
        pv.w = ex2(-L2E * (W0 * h0v[3] + bb)); qv.w = ex2(-L2E * (W1 * h0v[3]));
        *(float4*)&pL[i * PAD + j] = pv;
        *(float4*)&qL[i * PAD + j] = qv;
    }
    __syncthreads();
    att2q(pL + lane * PAD, qL, row0, lane, mbuf, mg);
    __syncthreads();
    if (wv == 0) v1buf[lane] = exch_soft(mbuf, mg, half, lane, p1s[0], p1t[0], false);
    __syncthreads();

    // ======== stage C: X[r][k] = h1[k][r] * v1[k] (transposed scalar stores) ====
    {
        const float W0 = p2W[0], W1 = p2W[1], bb = p2b[0];
        const float sc = v1buf[i];
#pragma unroll
        for (int t = 0; t < 4; ++t) {
            float hv = h1v[t] * sc;
            pL[(j + t) * PAD + i] = ex2(-L2E * (W0 * hv + bb));
            qL[(j + t) * PAD + i] = ex2(-L2E * (W1 * hv));
        }
    }
    __syncthreads();
    att2q(pL + lane * PAD, qL, row0, lane, mbuf, mg + A);
    __syncthreads();
    if (wv == 0) v2buf[lane] = exch_soft(mbuf, mg + A, half, lane, p2s[0], p2t[0], false);
    __syncthreads();

    // ======== stage D: X = h0 * v1[i] * v2[j] (row-major, float4 stores) ====
    {
        const float W0 = oW[0], W1 = oW[1], bb = ob[0];
        const float sc = v1buf[i];
        const float4 v2q = *(const float4*)&v2buf[j];
        float hv0 = h0v[0] * sc * v2q.x, hv1 = h0v[1] * sc * v2q.y;
        float hv2 = h0v[2] * sc * v2q.z, hv3 = h0v[3] * sc * v2q.w;
        float4 pv, qv;
        pv.x = ex2(-L2E * (W0 * hv0 + bb)); qv.x = ex2(-L2E * (W1 * hv0));
        pv.y = ex2(-L2E * (W0 * hv1 + bb)); qv.y = ex2(-L2E * (W1 * hv1));
        pv.z = ex2(-L2E * (W0 * hv2 + bb)); qv.z = ex2(-L2E * (W1 * hv2));
        pv.w = ex2(-L2E * (W0 * hv3 + bb)); qv.w = ex2(-L2E * (W1 * hv3));
        *(float4*)&pL[i * PAD + j] = pv;
        *(float4*)&qL[i * PAD + j] = qv;
    }
    __syncthreads();
    att2q(pL + lane * PAD, qL, row0, lane, mbuf, mg + 2 * A);
    __syncthreads();

    // ======== final softmax (is_last); each block writes its 32 outputs ====
    if (wv == 0) {
        float r = exch_soft(mbuf, mg + 2 * A, half, lane, os[0], ot[0], true);
        if ((lane >> 5) == half) out[(size_t)n * A + lane] = r;
    }
}

extern "C" void kernel_launch(void* const* d_in, const int* in_sizes, int n_in,
                              void* d_out, int out_size, void* d_ws, size_t ws_size,
                              hipStream_t stream)
{
    (void)n_in; (void)out_size; (void)ws_size;
    const float* x   = (const float*)d_in[0];
    const float* fcW = (const float*)d_in[1];
    const float* fcb = (const float*)d_in[2];
    const float* p1W = (const float*)d_in[3];
    const float* p1b = (const float*)d_in[4];
    const float* p1s = (const float*)d_in[5];
    const float* p1t = (const float*)d_in[6];
    const float* p2W = (const float*)d_in[7];
    const float* p2b = (const float*)d_in[8];
    const float* p2s = (const float*)d_in[9];
    const float* p2t = (const float*)d_in[10];
    const float* oW  = (const float*)d_in[11];
    const float* ob  = (const float*)d_in[12];
    const float* os  = (const float*)d_in[13];
    const float* ot  = (const float*)d_in[14];
    float* out = (float*)d_out;

    const int N = in_sizes[0] / (2 * A * A);   // 128
    float* mglob = (float*)d_ws;               // [N][3][64]

    attn_half<<<2 * N, 1024, 0, stream>>>(x, fcW, fcb,
                                          p1W, p1b, p1s, p1t,
                                          p2W, p2b, p2s, p2t,
                                          oW, ob, os, ot, mglob, out);
}